// Round 1
// baseline (975.420 us; speedup 1.0000x reference)
//
#include <hip/hip_runtime.h>
#include <stdint.h>

// ---------------------------------------------------------------------------
// UnionBoxesAndFeats: 8-kernel pipeline
//  k_setup   : per-pair union-roi sample coords + rect coverage vectors
//  k_fmapt   : fmap (C,H,W) -> (H*W, C) so RoIAlign tap reads coalesce over c
//  k_conv1   : per-pair MFMA GEMM (M=256pad,N=128,K=128pad): rect im2col built
//              in LDS from cy/cx outer product; epilogue: +b1, relu, per-ch
//              stats partials, 3x3/s2 maxpool of RAW relu  -> p1 bf16 [m49][128]
//  k_stats1  : reduce partials -> a1,c1 (bn1 affine)
//  k_prepb2  : W2s[o][tap*128+c] = a1[c]*W2 (bf16)  +  T2t[pos][o] = b2 +
//              sum_{inbounds taps} sum_c c1[c]*W2   (the bn1-shift/pad bias)
//  k_conv2   : implicit GEMM M=200704,N=256,K=1152 (9 taps x 128c), A gathered
//              from p1 w/ zero-page for padding; epilogue: +T2t, relu, stats
//              partials, z+ bf16 [m][256]
//  k_stats2  : reduce -> a2,c2
//  k_final   : out = RoIAlign(union roi) + a2*z+ + c2   (coalesced via LDS)
// ---------------------------------------------------------------------------

typedef __attribute__((ext_vector_type(8))) short bf16x8;   // 8 bf16 = 4 VGPR (guide §3)
typedef __attribute__((ext_vector_type(4))) float f32x4;

__device__ __forceinline__ uint16_t f2b(float f) {          // fp32 -> bf16 RNE
  uint32_t x = __float_as_uint(f);
  return (uint16_t)((x + 0x7fffu + ((x >> 16) & 1u)) >> 16);
}
__device__ __forceinline__ float b2f(uint16_t u) {
  return __uint_as_float(((uint32_t)u) << 16);
}
__device__ __forceinline__ f32x4 mfma16(bf16x8 a, bf16x8 b, f32x4 c) {
  return __builtin_amdgcn_mfma_f32_16x16x32_bf16(a, b, c, 0, 0, 0);
}

#define NPAIR 4096

// ---------------------------------------------------------------- k_setup ---
__global__ void k_setup(const float* __restrict__ rois, const int* __restrict__ ui,
                        float* __restrict__ paird, float* __restrict__ zp)
{
  int p = blockIdx.x * 256 + threadIdx.x;
  if (blockIdx.x == 0 && threadIdx.x < 64) zp[threadIdx.x] = 0.f;  // zero page (ws is 0xAA-poisoned)
  if (p >= NPAIR) return;
  int i0 = ui[2*p+0], i1 = ui[2*p+1];
  const float* r0 = rois + i0*5;
  const float* r1 = rois + i1*5;
  float ax1=r0[1], ay1=r0[2], ax2=r0[3], ay2=r0[4];
  float bx1=r1[1], by1=r1[2], bx2=r1[3], by2=r1[4];
  float ux1=fminf(ax1,bx1), uy1=fminf(ay1,by1);
  float ux2=fmaxf(ax2,bx2), uy2=fmaxf(ay2,by2);
  float* pd = paird + (size_t)p*136;
  const float sc = 1.0f/16.0f;
  #pragma unroll
  for (int j=0;j<7;j++){
    float t = (float)j * (1.0f/6.0f);
    float xs = ux1*sc*(1.0f-t) + ux2*sc*t;
    xs = fminf(fmaxf(xs, 0.0f), 36.0f);
    float xf = floorf(xs);
    pd[j] = xf; pd[7+j] = xs - xf;
    float ys = uy1*sc*(1.0f-t) + uy2*sc*t;
    ys = fminf(fmaxf(ys, 0.0f), 36.0f);
    float yf = floorf(ys);
    pd[14+j] = yf; pd[21+j] = ys - yf;
  }
  float w = ux2-ux1, h = uy2-uy1;
  float x1a[2] = {ax1,bx1}, x2a[2] = {ax2,bx2};
  float y1a[2] = {ay1,by1}, y2a[2] = {ay2,by2};
  #pragma unroll
  for (int k=0;k<2;k++){
    float sx1 = (x1a[k]-ux1)/w*27.0f;
    float sx2 = (x2a[k]-ux1)/w*27.0f;
    float sy1 = (y1a[k]-uy1)/h*27.0f;
    float sy2 = (y2a[k]-uy1)/h*27.0f;
    for (int g=0; g<27; g++){
      float gg = (float)g;
      float cx = fminf(fmaxf(fminf(gg+1.0f, sx2) - fmaxf(gg, sx1), 0.0f), 1.0f);
      float cy = fminf(fmaxf(fminf(gg+1.0f, sy2) - fmaxf(gg, sy1), 0.0f), 1.0f);
      pd[28 + k*27 + g] = cx;   // cx[2][27]
      pd[82 + k*27 + g] = cy;   // cy[2][27]
    }
  }
}

// ---------------------------------------------------------------- k_fmapt ---
__global__ void k_fmapt(const float* __restrict__ fmap, float* __restrict__ fmt){
  int idx = blockIdx.x*256 + threadIdx.x;
  if (idx >= 256*1369) return;
  int o = idx / 1369;
  int yx = idx - o*1369;
  fmt[yx*256 + o] = fmap[idx];
}

// ---------------------------------------------------------------- k_conv1 ---
// one block per pair. M=256(196 real rows, (Y,X) of 14x14), N=128, K=128(98 real)
__global__ __launch_bounds__(256) void k_conv1(
    const float* __restrict__ paird, const float* __restrict__ W1,
    const float* __restrict__ b1v,
    uint16_t* __restrict__ p1, float* __restrict__ part1)
{
  __shared__ __align__(128) char lds[58368];
  uint16_t* smA  = (uint16_t*)lds;             // [256][72] bf16 (64-k chunk + 8 pad)
  uint16_t* smB  = (uint16_t*)(lds + 36864);   // [128][72] bf16
  uint16_t* smY  = (uint16_t*)lds;             // [196][132] bf16 (epilogue, overlaps A/B)
  float* smCXY   = (float*)(lds + 55296);      // 108
  float* smB1    = (float*)(lds + 55728);      // 128
  float* smStat  = (float*)(lds + 56240);      // 512
  const int tid = threadIdx.x;
  const int n = blockIdx.x;
  const int wv = tid >> 6, lane = tid & 63, quad = lane >> 4, l15 = lane & 15;

  if (tid < 108) smCXY[tid] = paird[(size_t)n*136 + 28 + tid];
  if (tid >= 128) smB1[tid-128] = b1v[tid-128];
  __syncthreads();

  // per-row (m = tid) gathered coverage vectors; rect[c][y'][x'] = cy*cx - 0.5 (0 outside)
  float cyv0[7], cyv1[7], cxv0[7], cxv1[7], byv[7], nbx[7];
  {
    int m = tid;
    int Y = m / 14, X = m - Y*14;
    bool rv = (m < 196);
    #pragma unroll
    for (int d=0; d<7; d++){
      int yq = 2*Y + d - 3;
      bool iy = rv && ((unsigned)yq < 27u);
      int yqc = yq < 0 ? 0 : (yq > 26 ? 26 : yq);
      byv[d]  = iy ? 1.0f : 0.0f;
      cyv0[d] = iy ? smCXY[54 + yqc] : 0.0f;
      cyv1[d] = iy ? smCXY[81 + yqc] : 0.0f;
      int xq = 2*X + d - 3;
      bool ix = rv && ((unsigned)xq < 27u);
      int xqc = xq < 0 ? 0 : (xq > 26 ? 26 : xq);
      nbx[d]  = ix ? -0.5f : 0.0f;
      cxv0[d] = ix ? smCXY[xqc] : 0.0f;
      cxv1[d] = ix ? smCXY[27 + xqc] : 0.0f;
    }
  }

  f32x4 zero4 = {0.f,0.f,0.f,0.f};
  f32x4 acc[4][8];
  #pragma unroll
  for (int i=0;i<4;i++)
    #pragma unroll
    for (int j=0;j<8;j++) acc[i][j] = zero4;

  #pragma unroll
  for (int chunk=0; chunk<2; chunk++){
    __syncthreads();
    // stage W1 chunk -> smB[o][k]  (k = c*49+dy*7+dx, zero-padded to 128)
    {
      int o = tid >> 1, hf = tid & 1;
      #pragma unroll
      for (int g=0; g<4; g++){
        uint32_t wd[4];
        #pragma unroll
        for (int h2=0; h2<4; h2++){
          uint16_t lo=0, hi=0;
          #pragma unroll
          for (int e=0; e<2; e++){
            int kl = hf*32 + g*8 + h2*2 + e;
            int k = chunk*64 + kl;
            float v = 0.0f;
            if (k < 98) v = W1[o*98 + k];
            uint16_t bb = f2b(v);
            if (e==0) lo = bb; else hi = bb;
          }
          wd[h2] = (uint32_t)lo | ((uint32_t)hi << 16);
        }
        *(uint4*)(smB + o*72 + hf*32 + g*8) = make_uint4(wd[0],wd[1],wd[2],wd[3]);
      }
    }
    // generate A chunk: row m = tid, val = cy*cx - 0.5*inb (0 oob)
    {
      uint16_t* rowp = smA + tid*72;
      #pragma unroll
      for (int cc=0; cc<8; cc++){
        uint32_t wd[4];
        #pragma unroll
        for (int h2=0; h2<4; h2++){
          uint16_t lo=0, hi=0;
          #pragma unroll
          for (int e=0; e<2; e++){
            int k = chunk*64 + cc*8 + h2*2 + e;
            float v = 0.0f;
            if (k < 98){
              int c = k / 49;
              int r = k - c*49;
              int dy = r / 7, dx = r - dy*7;
              float cy = c ? cyv1[dy] : cyv0[dy];
              float cx = c ? cxv1[dx] : cxv0[dx];
              v = fmaf(cy, cx, byv[dy]*nbx[dx]);
            }
            uint16_t bb = f2b(v);
            if (e==0) lo = bb; else hi = bb;
          }
          wd[h2] = (uint32_t)lo | ((uint32_t)hi << 16);
        }
        *(uint4*)(rowp + cc*8) = make_uint4(wd[0],wd[1],wd[2],wd[3]);
      }
    }
    __syncthreads();
    #pragma unroll
    for (int ks=0; ks<2; ks++){
      bf16x8 af[4];
      #pragma unroll
      for (int i=0;i<4;i++)
        af[i] = *(const bf16x8*)(smA + (wv*64 + i*16 + l15)*72 + ks*32 + quad*8);
      #pragma unroll
      for (int j=0;j<8;j++){
        bf16x8 bb = *(const bf16x8*)(smB + (j*16 + l15)*72 + ks*32 + quad*8);
        #pragma unroll
        for (int i=0;i<4;i++)
          acc[i][j] = mfma16(af[i], bb, acc[i][j]);
      }
    }
  }
  __syncthreads();
  // epilogue: y = relu(acc + b1) -> smY bf16  (C/D layout: col=lane&15, row=quad*4+reg)
  #pragma unroll
  for (int i=0;i<4;i++){
    #pragma unroll
    for (int reg=0; reg<4; reg++){
      int row = wv*64 + i*16 + quad*4 + reg;
      if (row < 196){
        #pragma unroll
        for (int j=0;j<8;j++){
          int col = j*16 + l15;
          float v = fmaxf(acc[i][j][reg] + smB1[col], 0.0f);
          smY[row*132 + col] = f2b(v);
        }
      }
    }
  }
  __syncthreads();
  // per-channel stats partials (sum, sumsq over 196 positions)
  {
    int o = tid & 127, hh = tid >> 7;
    float S = 0.f, Q = 0.f;
    for (int r = hh*98; r < hh*98 + 98; r++){
      float v = b2f(smY[r*132 + o]);
      S += v; Q += v*v;
    }
    smStat[o*4 + hh*2 + 0] = S;
    smStat[o*4 + hh*2 + 1] = Q;
  }
  // maxpool 3x3 s2 p1 of RAW relu (bn affine applied later; valid since g1>0)
  for (int it=0; it<25; it++){
    int idx = tid + it*256;
    if (idx < 6272){
      int pos = idx >> 7, o = idx & 127;
      int Yp = pos / 7, Xp = pos - Yp*7;
      int yb = 2*Yp - 1, xb = 2*Xp - 1;
      float mx = 0.0f;   // relu values >= 0
      #pragma unroll
      for (int a=0;a<3;a++){
        int yy = yb + a;
        if ((unsigned)yy < 14u){
          #pragma unroll
          for (int b=0;b<3;b++){
            int xx = xb + b;
            if ((unsigned)xx < 14u)
              mx = fmaxf(mx, b2f(smY[(yy*14+xx)*132 + o]));
          }
        }
      }
      p1[((size_t)n*49 + pos)*128 + o] = f2b(mx);
    }
  }
  __syncthreads();
  if (tid < 128){
    float S = smStat[tid*4+0] + smStat[tid*4+2];
    float Q = smStat[tid*4+1] + smStat[tid*4+3];
    part1[((size_t)n*128 + tid)*2 + 0] = S;
    part1[((size_t)n*128 + tid)*2 + 1] = Q;
  }
}

// --------------------------------------------------------------- k_stats1 ---
__global__ void k_stats1(const float* __restrict__ part1, const float* __restrict__ g1,
                         const float* __restrict__ be1, float* __restrict__ ab1)
{
  __shared__ float sS[256], sQ[256];
  int ch = blockIdx.x, t = threadIdx.x;
  float S=0.f, Q=0.f;
  for (int i=t; i<4096; i+=256){
    S += part1[((size_t)i*128 + ch)*2 + 0];
    Q += part1[((size_t)i*128 + ch)*2 + 1];
  }
  sS[t]=S; sQ[t]=Q;
  __syncthreads();
  for (int s=128; s>0; s>>=1){
    if (t < s){ sS[t]+=sS[t+s]; sQ[t]+=sQ[t+s]; }
    __syncthreads();
  }
  if (t==0){
    float N = 4096.0f*196.0f;
    float mean = sS[0]/N;
    float var = sQ[0]/N - mean*mean;
    float a = g1[ch] * rsqrtf(var + 1e-5f);
    ab1[ch*2+0] = a;
    ab1[ch*2+1] = be1[ch] - mean*a;
  }
}

// --------------------------------------------------------------- k_prepb2 ---
__global__ void k_prepb2(const float* __restrict__ W2, const float* __restrict__ b2v,
                         const float* __restrict__ ab1,
                         uint16_t* __restrict__ W2s, uint16_t* __restrict__ T2t)
{
  __shared__ float sA[128], sC[128], sU[9];
  int o = blockIdx.x, t = threadIdx.x;
  if (t < 128){ sA[t] = ab1[t*2+0]; sC[t] = ab1[t*2+1]; }
  __syncthreads();
  const float* w = W2 + (size_t)o*1152;
  for (int k=t; k<1152; k+=256){
    int c = k & 127, tap = k >> 7;
    W2s[(size_t)o*1152 + k] = f2b(w[c*9 + tap] * sA[c]);
  }
  if (t < 9){
    float u = 0.f;
    for (int c=0;c<128;c++) u += sC[c] * w[c*9 + t];
    sU[t] = u;
  }
  __syncthreads();
  if (t < 49){
    int y = t / 7, x = t - (t/7)*7;
    float s = b2v[o];
    #pragma unroll
    for (int dy=0;dy<3;dy++)
      #pragma unroll
      for (int dx=0;dx<3;dx++){
        int yy = y+dy-1, xx = x+dx-1;
        if ((unsigned)yy < 7u && (unsigned)xx < 7u) s += sU[dy*3+dx];
      }
    T2t[t*256 + o] = f2b(s);
  }
}

// ---------------------------------------------------------------- k_conv2 ---
// implicit GEMM: M=200704 (tile 128), N=256, K=1152 (tap-major, 36 steps of 32)
__global__ __launch_bounds__(256) void k_conv2(
    const uint16_t* __restrict__ p1, const uint16_t* __restrict__ W2s,
    const uint16_t* __restrict__ T2t, const float* __restrict__ zpf,
    uint16_t* __restrict__ zplus, float* __restrict__ part2)
{
  __shared__ __align__(128) char lds[57856];
  uint16_t* smA = (uint16_t*)lds;             // [128][40] bf16 (32k + 8 pad)
  uint16_t* smB = (uint16_t*)(lds + 10240);   // [256][40]
  uint16_t* smZ = (uint16_t*)lds;             // [64][256] epilogue half-tile
  uint16_t* smT = (uint16_t*)(lds + 32768);   // [49][256] bias table
  const uint16_t* zp16 = (const uint16_t*)zpf;
  const int tid = threadIdx.x;
  const int m0 = blockIdx.x * 128;
  const int rq = tid & 3, r1 = tid >> 2;
  const int wv = tid >> 6, lane = tid & 63, quad = lane >> 4, l15 = lane & 15;

  int mA = m0 + r1;       int nA = mA / 49;  int pA = mA - nA*49;  int yA = pA/7, xA = pA - (pA/7)*7;
  int mBr = m0 + r1 + 64; int nB = mBr / 49; int pB = mBr - nB*49; int yB = pB/7, xB = pB - (pB/7)*7;

  uint4 ra0, ra1, rb0, rb1, rb2, rb3;
  auto loadstep = [&](int s){
    int tap = s >> 2;
    int c0 = (s & 3) << 5;
    int dyq = tap / 3;
    int dy = dyq - 1;
    int dx = tap - dyq*3 - 1;
    {
      int yy = yA + dy, xx = xA + dx;
      const uint16_t* pa = ((unsigned)yy < 7u && (unsigned)xx < 7u)
          ? (p1 + (size_t)((nA*49 + yy*7 + xx)*128 + c0 + rq*8))
          : (zp16 + rq*8);
      ra0 = *(const uint4*)pa;
    }
    {
      int yy = yB + dy, xx = xB + dx;
      const uint16_t* pa = ((unsigned)yy < 7u && (unsigned)xx < 7u)
          ? (p1 + (size_t)((nB*49 + yy*7 + xx)*128 + c0 + rq*8))
          : (zp16 + rq*8);
      ra1 = *(const uint4*)pa;
    }
    size_t bb = (size_t)r1*1152 + (size_t)(s*32) + rq*8;
    rb0 = *(const uint4*)(W2s + bb);
    rb1 = *(const uint4*)(W2s + bb + (size_t)64*1152);
    rb2 = *(const uint4*)(W2s + bb + (size_t)128*1152);
    rb3 = *(const uint4*)(W2s + bb + (size_t)192*1152);
  };
  loadstep(0);

  f32x4 zero4 = {0.f,0.f,0.f,0.f};
  f32x4 acc0[16], acc1[16];
  #pragma unroll
  for (int j=0;j<16;j++){ acc0[j] = zero4; acc1[j] = zero4; }
  const uint16_t* arow0 = smA + (wv*32 + l15)*40 + quad*8;
  const uint16_t* arow1 = arow0 + 16*40;

  for (int s=0; s<36; s++){
    __syncthreads();
    *(uint4*)(smA + r1*40 + rq*8) = ra0;
    *(uint4*)(smA + (r1+64)*40 + rq*8) = ra1;
    *(uint4*)(smB + r1*40 + rq*8) = rb0;
    *(uint4*)(smB + (r1+64)*40 + rq*8) = rb1;
    *(uint4*)(smB + (r1+128)*40 + rq*8) = rb2;
    *(uint4*)(smB + (r1+192)*40 + rq*8) = rb3;
    __syncthreads();
    if (s < 35) loadstep(s+1);       // prefetch overlaps MFMA
    bf16x8 a0 = *(const bf16x8*)arow0;
    bf16x8 a1 = *(const bf16x8*)arow1;
    #pragma unroll
    for (int j=0;j<16;j++){
      bf16x8 bb = *(const bf16x8*)(smB + (j*16 + l15)*40 + quad*8);
      acc0[j] = mfma16(a0, bb, acc0[j]);
      acc1[j] = mfma16(a1, bb, acc1[j]);
    }
  }
  __syncthreads();
  #pragma unroll
  for (int i=0;i<7;i++){
    int ch = tid + i*256;
    if (ch < 1568) ((uint4*)smT)[ch] = ((const uint4*)T2t)[ch];
  }
  float S=0.f, Q=0.f;
  #pragma unroll
  for (int half=0; half<2; half++){
    __syncthreads();
    if ((wv >> 1) == half){
      int iw = wv & 1;
      #pragma unroll
      for (int i=0;i<2;i++){
        #pragma unroll
        for (int reg=0; reg<4; reg++){
          int rl = iw*32 + i*16 + quad*4 + reg;
          int m = m0 + half*64 + rl;
          int pos = m % 49;
          const uint16_t* tr = smT + pos*256;
          uint16_t* zr = smZ + rl*256;
          #pragma unroll
          for (int j=0;j<16;j++){
            int col = j*16 + l15;
            float z = (i==0 ? acc0[j][reg] : acc1[j][reg]) + b2f(tr[col]);
            zr[col] = f2b(fmaxf(z, 0.0f));
          }
        }
      }
    }
    __syncthreads();
    #pragma unroll
    for (int i2=0;i2<8;i2++){
      int ch = tid + i2*256;
      int row = ch >> 5, off = ch & 31;
      *(uint4*)(zplus + ((size_t)(m0 + half*64 + row))*256 + off*8) = ((const uint4*)smZ)[ch];
    }
    for (int r=0;r<64;r++){
      float v = b2f(smZ[r*256 + tid]);
      S += v; Q += v*v;
    }
  }
  part2[((size_t)blockIdx.x*256 + tid)*2 + 0] = S;
  part2[((size_t)blockIdx.x*256 + tid)*2 + 1] = Q;
}

// --------------------------------------------------------------- k_stats2 ---
__global__ void k_stats2(const float* __restrict__ part2, const float* __restrict__ g2,
                         const float* __restrict__ be2, float* __restrict__ ab2)
{
  __shared__ float sS[256], sQ[256];
  int ch = blockIdx.x, t = threadIdx.x;
  float S=0.f, Q=0.f;
  for (int i=t; i<1568; i+=256){
    S += part2[((size_t)i*256 + ch)*2 + 0];
    Q += part2[((size_t)i*256 + ch)*2 + 1];
  }
  sS[t]=S; sQ[t]=Q;
  __syncthreads();
  for (int s=128; s>0; s>>=1){
    if (t < s){ sS[t]+=sS[t+s]; sQ[t]+=sQ[t+s]; }
    __syncthreads();
  }
  if (t==0){
    float N = 200704.0f;
    float mean = sS[0]/N;
    float var = sQ[0]/N - mean*mean;
    float a = g2[ch] * rsqrtf(var + 1e-5f);
    ab2[ch*2+0] = a;
    ab2[ch*2+1] = be2[ch] - mean*a;
  }
}

// ---------------------------------------------------------------- k_final ---
__global__ __launch_bounds__(256) void k_final(
    const float* __restrict__ paird, const float* __restrict__ fmt,
    const uint16_t* __restrict__ zplus, const float* __restrict__ ab2,
    float* __restrict__ out)
{
  __shared__ float smRes[12544];     // [o][pos] transpose buffer
  __shared__ int   smTI[196];
  __shared__ float smTW[196];
  int n = blockIdx.x, tid = threadIdx.x;
  if (tid < 49){
    const float* pd = paird + (size_t)n*136;
    int py = tid / 7, px = tid - (tid/7)*7;
    float x0 = pd[px],    wx = pd[7+px];
    float y0 = pd[14+py], wy = pd[21+py];
    int x0i = (int)x0, y0i = (int)y0;
    int x1i = min(x0i+1, 36), y1i = min(y0i+1, 36);
    smTI[tid*4+0] = (y0i*37+x0i)*256;
    smTI[tid*4+1] = (y0i*37+x1i)*256;
    smTI[tid*4+2] = (y1i*37+x0i)*256;
    smTI[tid*4+3] = (y1i*37+x1i)*256;
    smTW[tid*4+0] = (1.f-wy)*(1.f-wx);
    smTW[tid*4+1] = (1.f-wy)*wx;
    smTW[tid*4+2] = wy*(1.f-wx);
    smTW[tid*4+3] = wy*wx;
  }
  float a2 = ab2[tid*2+0], c2 = ab2[tid*2+1];   // tid == channel o
  __syncthreads();
  const uint16_t* zrow = zplus + (size_t)n*49*256 + tid;
  int o = tid;
  for (int pos=0; pos<49; pos++){
    float v = smTW[pos*4+0]*fmt[smTI[pos*4+0]+o]
            + smTW[pos*4+1]*fmt[smTI[pos*4+1]+o]
            + smTW[pos*4+2]*fmt[smTI[pos*4+2]+o]
            + smTW[pos*4+3]*fmt[smTI[pos*4+3]+o];
    float z = b2f(zrow[(size_t)pos*256]);
    smRes[o*49 + pos] = v + a2*z + c2;
  }
  __syncthreads();
  float* op = out + (size_t)n*12544;
  for (int i=0;i<49;i++){
    int f = tid + i*256;
    op[f] = smRes[f];
  }
}

// ----------------------------------------------------------- kernel_launch --
extern "C" void kernel_launch(void* const* d_in, const int* in_sizes, int n_in,
                              void* d_out, int out_size, void* d_ws, size_t ws_size,
                              hipStream_t stream)
{
  const float* fmap = (const float*)d_in[0];
  const float* rois = (const float*)d_in[1];
  const int*   ui   = (const int*)d_in[2];
  const float* W1   = (const float*)d_in[3];
  const float* b1   = (const float*)d_in[4];
  const float* g1   = (const float*)d_in[5];
  const float* be1  = (const float*)d_in[6];
  const float* W2   = (const float*)d_in[7];
  const float* b2   = (const float*)d_in[8];
  const float* g2   = (const float*)d_in[9];
  const float* be2  = (const float*)d_in[10];
  float* out = (float*)d_out;
  char* ws = (char*)d_ws;

  constexpr size_t OFF_ZERO = 0;                             // 256 B zero page
  constexpr size_t OFF_PAIR = 256;                           // 4096*136*4
  constexpr size_t OFF_FMT  = OFF_PAIR + 4096u*136*4;        // 350464*4
  constexpr size_t OFF_P1   = OFF_FMT + 350464u*4;           // 200704*128*2
  constexpr size_t OFF_ZP   = OFF_P1 + 200704u*128*2;        // 200704*256*2
  constexpr size_t OFF_W2S  = OFF_ZP + (size_t)200704*256*2; // 294912*2
  constexpr size_t OFF_T2   = OFF_W2S + 294912u*2;           // 12544*2
  constexpr size_t OFF_S1   = OFF_T2 + 12544u*2;             // 4096*128*2*4
  constexpr size_t OFF_AB1  = OFF_S1 + 4096u*128*2*4;        // 128*2*4
  constexpr size_t OFF_S2   = OFF_AB1 + 1024;                // 1568*256*2*4
  constexpr size_t OFF_AB2  = OFF_S2 + 1568u*256*2*4;        // 256*2*4

  float*    zp    = (float*)(ws + OFF_ZERO);
  float*    pair  = (float*)(ws + OFF_PAIR);
  float*    fmt   = (float*)(ws + OFF_FMT);
  uint16_t* p1    = (uint16_t*)(ws + OFF_P1);
  uint16_t* zplus = (uint16_t*)(ws + OFF_ZP);
  uint16_t* W2s   = (uint16_t*)(ws + OFF_W2S);
  uint16_t* T2t   = (uint16_t*)(ws + OFF_T2);
  float*    part1 = (float*)(ws + OFF_S1);
  float*    ab1   = (float*)(ws + OFF_AB1);
  float*    part2 = (float*)(ws + OFF_S2);
  float*    ab2   = (float*)(ws + OFF_AB2);

  k_setup <<<16,   256, 0, stream>>>(rois, ui, pair, zp);
  k_fmapt <<<1369, 256, 0, stream>>>(fmap, fmt);
  k_conv1 <<<4096, 256, 0, stream>>>(pair, W1, b1, p1, part1);
  k_stats1<<<128,  256, 0, stream>>>(part1, g1, be1, ab1);
  k_prepb2<<<256,  256, 0, stream>>>(W2, b2, ab1, W2s, T2t);
  k_conv2 <<<1568, 256, 0, stream>>>(p1, W2s, T2t, zp, zplus, part2);
  k_stats2<<<256,  256, 0, stream>>>(part2, g2, be2, ab2);
  k_final <<<4096, 256, 0, stream>>>(pair, fmt, zplus, ab2, out);
}

// Round 2
// 726.652 us; speedup vs baseline: 1.3423x; 1.3423x over previous
//
#include <hip/hip_runtime.h>
#include <hip/hip_bf16.h>
#include <stdint.h>

// ---------------------------------------------------------------------------
// UnionBoxesAndFeats pipeline (R2):
//  k_setup   : per-pair union-roi sample coords + rect coverage vectors
//  k_prepw1  : W1 fp32 -> bf16 [128 o][128 k], k = c*64 + dy*8 + dx (padded)
//  k_fmapt   : fmap (C,H,W) -> (H*W, C), LDS-tiled transpose (both coalesced)
//  k_conv1   : per-pair MFMA GEMM, operand-swapped (D rows = out-channel) so
//              epilogue packs b64 LDS writes; A built from separable coverage
//              with compile-time (dy,dx); relu+bias; stats partials; 3x3/s2
//              maxpool via packed u16 integer max (values >= 0) -> p1 bf16
//  k_stats1  : reduce partials -> a1,c1 (bn1 affine)
//  k_prepb2  : W2s = a1*W2 (bf16), T2t[pos][o] = b2 + pad-aware bn1-shift term
//  k_conv2   : implicit GEMM M=200704,N=256,K=1152; 64x128 wave tiles
//  k_stats2  : reduce -> a2,c2
//  k_final   : out = RoIAlign(union roi) + a2*z+ + c2
// ---------------------------------------------------------------------------

typedef __attribute__((ext_vector_type(8))) short bf16x8;
typedef __attribute__((ext_vector_type(4))) float f32x4;
typedef __attribute__((ext_vector_type(2))) unsigned short u16x2;

__device__ __forceinline__ uint16_t f2b(float f) {          // fp32 -> bf16 RNE
  uint32_t x = __float_as_uint(f);
  return (uint16_t)((x + 0x7fffu + ((x >> 16) & 1u)) >> 16);
}
__device__ __forceinline__ float b2f(uint16_t u) {
  return __uint_as_float(((uint32_t)u) << 16);
}
__device__ __forceinline__ uint32_t pk2(float a, float b) { // packed RNE pair
  __hip_bfloat162 h = __float22bfloat162_rn(make_float2(a, b));
  union { __hip_bfloat162 h; uint32_t u; } cvt; cvt.h = h; return cvt.u;
}
__device__ __forceinline__ f32x4 mfma16(bf16x8 a, bf16x8 b, f32x4 c) {
  return __builtin_amdgcn_mfma_f32_16x16x32_bf16(a, b, c, 0, 0, 0);
}

#define NPAIR 4096

// ---------------------------------------------------------------- k_setup ---
__global__ void k_setup(const float* __restrict__ rois, const int* __restrict__ ui,
                        float* __restrict__ paird, float* __restrict__ zp)
{
  int p = blockIdx.x * 256 + threadIdx.x;
  if (blockIdx.x == 0 && threadIdx.x < 64) zp[threadIdx.x] = 0.f;  // zero page
  if (p >= NPAIR) return;
  int i0 = ui[2*p+0], i1 = ui[2*p+1];
  const float* r0 = rois + i0*5;
  const float* r1 = rois + i1*5;
  float ax1=r0[1], ay1=r0[2], ax2=r0[3], ay2=r0[4];
  float bx1=r1[1], by1=r1[2], bx2=r1[3], by2=r1[4];
  float ux1=fminf(ax1,bx1), uy1=fminf(ay1,by1);
  float ux2=fmaxf(ax2,bx2), uy2=fmaxf(ay2,by2);
  float* pd = paird + (size_t)p*136;
  const float sc = 1.0f/16.0f;
  #pragma unroll
  for (int j=0;j<7;j++){
    float t = (float)j * (1.0f/6.0f);
    float xs = ux1*sc*(1.0f-t) + ux2*sc*t;
    xs = fminf(fmaxf(xs, 0.0f), 36.0f);
    float xf = floorf(xs);
    pd[j] = xf; pd[7+j] = xs - xf;
    float ys = uy1*sc*(1.0f-t) + uy2*sc*t;
    ys = fminf(fmaxf(ys, 0.0f), 36.0f);
    float yf = floorf(ys);
    pd[14+j] = yf; pd[21+j] = ys - yf;
  }
  float w = ux2-ux1, h = uy2-uy1;
  float x1a[2] = {ax1,bx1}, x2a[2] = {ax2,bx2};
  float y1a[2] = {ay1,by1}, y2a[2] = {ay2,by2};
  #pragma unroll
  for (int k=0;k<2;k++){
    float sx1 = (x1a[k]-ux1)/w*27.0f;
    float sx2 = (x2a[k]-ux1)/w*27.0f;
    float sy1 = (y1a[k]-uy1)/h*27.0f;
    float sy2 = (y2a[k]-uy1)/h*27.0f;
    for (int g=0; g<27; g++){
      float gg = (float)g;
      float cx = fminf(fmaxf(fminf(gg+1.0f, sx2) - fmaxf(gg, sx1), 0.0f), 1.0f);
      float cy = fminf(fmaxf(fminf(gg+1.0f, sy2) - fmaxf(gg, sy1), 0.0f), 1.0f);
      pd[28 + k*27 + g] = cx;   // cx ch0@28, ch1@55
      pd[82 + k*27 + g] = cy;   // cy ch0@82, ch1@109
    }
  }
}

// --------------------------------------------------------------- k_prepw1 ---
// W1b[o][k], k = cch*64 + dy*8 + dx  (dy,dx in 0..6 real, slot 7 zero)
__global__ void k_prepw1(const float* __restrict__ W1, uint16_t* __restrict__ W1b)
{
  int idx = blockIdx.x*256 + threadIdx.x;   // 64 blocks -> 16384
  int o = idx >> 7, kk = idx & 127;
  int cch = kk >> 6, r = kk & 63, dy = r >> 3, dx = r & 7;
  float v = (dy < 7 && dx < 7) ? W1[o*98 + cch*49 + dy*7 + dx] : 0.f;
  W1b[idx] = f2b(v);
}

// ---------------------------------------------------------------- k_fmapt ---
// tiled transpose: 64 (yx) x 64 (o) tiles; grid (22, 4)
__global__ void k_fmapt(const float* __restrict__ fmap, float* __restrict__ fmt){
  __shared__ float tile[64][65];
  int yx0 = blockIdx.x * 64;
  int o0  = blockIdx.y * 64;
  int tx = threadIdx.x & 63, ty = threadIdx.x >> 6;
  #pragma unroll
  for (int i=0;i<16;i++){
    int oo = ty*16 + i;
    int yx = yx0 + tx;
    tile[oo][tx] = (yx < 1369) ? fmap[(size_t)(o0+oo)*1369 + yx] : 0.f;
  }
  __syncthreads();
  #pragma unroll
  for (int i=0;i<16;i++){
    int r = ty*16 + i;
    int yx = yx0 + r;
    if (yx < 1369) fmt[(size_t)yx*256 + o0 + tx] = tile[tx][r];
  }
}

// ---------------------------------------------------------------- k_conv1 ---
// one block per pair, 512 threads. GEMM (o=128) x (m=256 pad, 196 real) x
// (k=128 pad, 98 real), operand-swapped: D rows = o, cols = m.
__global__ __launch_bounds__(512, 4) void k_conv1(
    const float* __restrict__ paird, const uint16_t* __restrict__ W1b,
    const float* __restrict__ b1v,
    uint16_t* __restrict__ p1, float* __restrict__ part1)
{
  __shared__ __align__(128) char lds[62976];
  uint16_t* smA  = (uint16_t*)lds;              // [256 m][72] per-64k chunk
  uint16_t* smB  = (uint16_t*)(lds + 36864);    // [128 o][72]
  uint16_t* smY  = (uint16_t*)lds;              // [196 m][132 o] epilogue (overlaps)
  float* cy0a = (float*)(lds + 55296);          // [14][8]
  float* cy1a = (float*)(lds + 55808);
  float* bya  = (float*)(lds + 56320);
  float* cx0a = (float*)(lds + 56832);
  float* cx1a = (float*)(lds + 57344);
  float* nbxa = (float*)(lds + 57856);
  float* smB1 = (float*)(lds + 58368);          // [128]
  float* smStat = (float*)(lds + 58880);        // [128][8]
  const int tid = threadIdx.x;
  const int n = blockIdx.x;
  const int wv = tid >> 6, lane = tid & 63, quad = lane >> 4, l15 = lane & 15;
  const float* pd = paird + (size_t)n*136;

  // phase 0: coverage lookup tables (slot dy/dx==7 -> 0)
  if (tid < 112){
    int Y = tid >> 3, dy = tid & 7;
    int yq = 2*Y + dy - 3;
    bool iy = (dy < 7) && ((unsigned)yq < 27u);
    int yqc = iy ? yq : 0;
    cy0a[tid] = iy ? pd[82+yqc]  : 0.f;
    cy1a[tid] = iy ? pd[109+yqc] : 0.f;
    bya[tid]  = iy ? 1.f : 0.f;
  } else if (tid >= 128 && tid < 240){
    int t2 = tid - 128;
    int X = t2 >> 3, dx = t2 & 7;
    int xq = 2*X + dx - 3;
    bool ix = (dx < 7) && ((unsigned)xq < 27u);
    int xqc = ix ? xq : 0;
    cx0a[t2] = ix ? pd[28+xqc] : 0.f;
    cx1a[t2] = ix ? pd[55+xqc] : 0.f;
    nbxa[t2] = ix ? -0.5f : 0.f;
  } else if (tid >= 256 && tid < 384){
    smB1[tid-256] = b1v[tid-256];
  }
  __syncthreads();

  const int m = tid & 255, h = tid >> 8;        // thread -> (A row, k-half)
  int Yr = m / 14, Xr = m - (m/14)*14;
  bool mv = (m < 196);
  int Yc = mv ? Yr : 0, Xc = mv ? Xr : 0;
  float byr[4], nbr[8];
  #pragma unroll
  for (int j=0;j<4;j++) byr[j] = mv ? bya[Yc*8 + h*4 + j] : 0.f;
  #pragma unroll
  for (int d=0;d<8;d++) nbr[d] = mv ? nbxa[Xc*8 + d] : 0.f;

  f32x4 zero4 = {0.f,0.f,0.f,0.f};
  f32x4 acc[8][2];
  #pragma unroll
  for (int io=0;io<8;io++){ acc[io][0] = zero4; acc[io][1] = zero4; }

  #pragma unroll
  for (int c=0;c<2;c++){
    // stage B chunk (bf16, already padded/ordered)
    {
      int o = tid >> 2, part = tid & 3;
      const uint4* src = (const uint4*)(W1b + o*128 + c*64);
      uint4* dst = (uint4*)(smB + o*72);
      dst[part*2]   = src[part*2];
      dst[part*2+1] = src[part*2+1];
    }
    // generate A chunk: k-local = dy*8+dx; per g, dy = h*4+g fixed
    {
      const float* cya = c ? cy1a : cy0a;
      const float* cxa = c ? cx1a : cx0a;
      float cyr[4], cxr[8];
      #pragma unroll
      for (int j=0;j<4;j++) cyr[j] = mv ? cya[Yc*8 + h*4 + j] : 0.f;
      #pragma unroll
      for (int d=0;d<8;d++) cxr[d] = mv ? cxa[Xc*8 + d] : 0.f;
      uint16_t* rowp = smA + m*72 + h*32;
      #pragma unroll
      for (int g=0; g<4; g++){
        uint32_t w[4];
        #pragma unroll
        for (int q=0; q<4; q++){
          float v0 = fmaf(cyr[g], cxr[q*2],   byr[g]*nbr[q*2]);
          float v1 = fmaf(cyr[g], cxr[q*2+1], byr[g]*nbr[q*2+1]);
          w[q] = pk2(v0, v1);
        }
        *(uint4*)(rowp + g*8) = make_uint4(w[0],w[1],w[2],w[3]);
      }
    }
    __syncthreads();
    #pragma unroll
    for (int ks=0; ks<2; ks++){
      bf16x8 rf0 = *(const bf16x8*)(smA + (wv*32      + l15)*72 + ks*32 + quad*8);
      bf16x8 rf1 = *(const bf16x8*)(smA + (wv*32 + 16 + l15)*72 + ks*32 + quad*8);
      #pragma unroll
      for (int io=0;io<8;io++){
        bf16x8 wf = *(const bf16x8*)(smB + (io*16 + l15)*72 + ks*32 + quad*8);
        acc[io][0] = mfma16(wf, rf0, acc[io][0]);
        acc[io][1] = mfma16(wf, rf1, acc[io][1]);
      }
    }
    __syncthreads();
  }

  // epilogue: y[m][o] = relu(acc + b1) -> smY, packed b64 writes
  #pragma unroll
  for (int io=0;io<8;io++){
    f32x4 bs = *(const f32x4*)(smB1 + io*16 + quad*4);
    #pragma unroll
    for (int jm=0;jm<2;jm++){
      int mm = wv*32 + jm*16 + l15;
      if (mm < 196){
        float v0 = fmaxf(acc[io][jm][0] + bs[0], 0.f);
        float v1 = fmaxf(acc[io][jm][1] + bs[1], 0.f);
        float v2 = fmaxf(acc[io][jm][2] + bs[2], 0.f);
        float v3 = fmaxf(acc[io][jm][3] + bs[3], 0.f);
        uint32_t w0 = pk2(v0,v1) & 0x7fff7fffu;   // clear -0 signs (u16 max safe)
        uint32_t w1 = pk2(v2,v3) & 0x7fff7fffu;
        *(uint2*)(smY + mm*132 + io*16 + quad*4) = make_uint2(w0, w1);
      }
    }
  }
  __syncthreads();

  // per-channel stats partials over 196 positions
  {
    int o = tid & 127, hh = tid >> 7;           // hh in 0..3, 49 rows each
    float S = 0.f, Q = 0.f;
    for (int r = hh*49; r < hh*49 + 49; r++){
      float v = b2f(smY[r*132 + o]);
      S += v; Q += v*v;
    }
    smStat[o*8 + hh*2 + 0] = S;
    smStat[o*8 + hh*2 + 1] = Q;
  }

  // maxpool 3x3 s2 of raw relu via packed u16 integer max (values >= 0)
  #pragma unroll
  for (int it=0; it<7; it++){
    int idx = tid + it*512;
    if (idx < 3136){
      int pos = idx >> 6, op2 = idx & 63;
      int Yp = pos / 7, Xp = pos - Yp*7;
      int yb = 2*Yp - 1, xb = 2*Xp - 1;
      u16x2 mx; mx.x = 0; mx.y = 0;
      #pragma unroll
      for (int a=0;a<3;a++){
        int yy = yb + a;
        if ((unsigned)yy < 14u){
          #pragma unroll
          for (int b=0;b<3;b++){
            int xx = xb + b;
            if ((unsigned)xx < 14u){
              u16x2 v = *(const u16x2*)(smY + (yy*14+xx)*132 + op2*2);
#if defined(__has_builtin) && __has_builtin(__builtin_elementwise_max)
              mx = __builtin_elementwise_max(mx, v);
#else
              mx.x = mx.x > v.x ? mx.x : v.x;
              mx.y = mx.y > v.y ? mx.y : v.y;
#endif
            }
          }
        }
      }
      *(uint32_t*)(p1 + ((size_t)n*49 + pos)*128 + op2*2) = *(uint32_t*)&mx;
    }
  }
  __syncthreads();
  if (tid < 128){
    float S = smStat[tid*8+0] + smStat[tid*8+2] + smStat[tid*8+4] + smStat[tid*8+6];
    float Q = smStat[tid*8+1] + smStat[tid*8+3] + smStat[tid*8+5] + smStat[tid*8+7];
    part1[((size_t)n*128 + tid)*2 + 0] = S;
    part1[((size_t)n*128 + tid)*2 + 1] = Q;
  }
}

// --------------------------------------------------------------- k_stats1 ---
__global__ void k_stats1(const float* __restrict__ part1, const float* __restrict__ g1,
                         const float* __restrict__ be1, float* __restrict__ ab1)
{
  __shared__ float sS[256], sQ[256];
  int ch = blockIdx.x, t = threadIdx.x;
  float S=0.f, Q=0.f;
  for (int i=t; i<4096; i+=256){
    S += part1[((size_t)i*128 + ch)*2 + 0];
    Q += part1[((size_t)i*128 + ch)*2 + 1];
  }
  sS[t]=S; sQ[t]=Q;
  __syncthreads();
  for (int s=128; s>0; s>>=1){
    if (t < s){ sS[t]+=sS[t+s]; sQ[t]+=sQ[t+s]; }
    __syncthreads();
  }
  if (t==0){
    float N = 4096.0f*196.0f;
    float mean = sS[0]/N;
    float var = sQ[0]/N - mean*mean;
    float a = g1[ch] * rsqrtf(var + 1e-5f);
    ab1[ch*2+0] = a;
    ab1[ch*2+1] = be1[ch] - mean*a;
  }
}

// --------------------------------------------------------------- k_prepb2 ---
__global__ void k_prepb2(const float* __restrict__ W2, const float* __restrict__ b2v,
                         const float* __restrict__ ab1,
                         uint16_t* __restrict__ W2s, uint16_t* __restrict__ T2t)
{
  __shared__ float sA[128], sC[128], sU[9];
  int o = blockIdx.x, t = threadIdx.x;
  if (t < 128){ sA[t] = ab1[t*2+0]; sC[t] = ab1[t*2+1]; }
  __syncthreads();
  const float* w = W2 + (size_t)o*1152;
  for (int k=t; k<1152; k+=256){
    int c = k & 127, tap = k >> 7;
    W2s[(size_t)o*1152 + k] = f2b(w[c*9 + tap] * sA[c]);
  }
  if (t < 9){
    float u = 0.f;
    for (int c=0;c<128;c++) u += sC[c] * w[c*9 + t];
    sU[t] = u;
  }
  __syncthreads();
  if (t < 49){
    int y = t / 7, x = t - (t/7)*7;
    float s = b2v[o];
    #pragma unroll
    for (int dy=0;dy<3;dy++)
      #pragma unroll
      for (int dx=0;dx<3;dx++){
        int yy = y+dy-1, xx = x+dx-1;
        if ((unsigned)yy < 7u && (unsigned)xx < 7u) s += sU[dy*3+dx];
      }
    T2t[t*256 + o] = f2b(s);
  }
}

// ---------------------------------------------------------------- k_conv2 ---
// implicit GEMM: M=200704 (tile 128), N=256, K=1152; 2x2 waves of 64Mx128N.
__global__ __launch_bounds__(256) void k_conv2(
    const uint16_t* __restrict__ p1, const uint16_t* __restrict__ W2s,
    const uint16_t* __restrict__ T2t, const float* __restrict__ zpf,
    uint16_t* __restrict__ zplus, float* __restrict__ part2)
{
  __shared__ __align__(128) char lds[57856];
  uint16_t* smA = (uint16_t*)lds;             // [128][40]
  uint16_t* smB = (uint16_t*)(lds + 10240);   // [256][40]
  uint16_t* smZ = (uint16_t*)lds;             // [64][256] epilogue half-tile
  uint16_t* smT = (uint16_t*)(lds + 32768);   // [49][256] bias table
  const uint16_t* zp16 = (const uint16_t*)zpf;
  const int tid = threadIdx.x;
  const int m0 = blockIdx.x * 128;
  const int rq = tid & 3, r1 = tid >> 2;
  const int wv = tid >> 6, lane = tid & 63, quad = lane >> 4, l15 = lane & 15;
  const int wm = wv >> 1, wn = wv & 1;

  int mA = m0 + r1;       int nA = mA / 49;  int pA = mA - nA*49;  int yA = pA/7, xA = pA - (pA/7)*7;
  int mBr = m0 + r1 + 64; int nB = mBr / 49; int pB = mBr - nB*49; int yB = pB/7, xB = pB - (pB/7)*7;

  uint4 ra0, ra1, rb0, rb1, rb2, rb3;
  auto loadstep = [&](int s){
    int tap = s >> 2;
    int c0 = (s & 3) << 5;
    int dyq = tap / 3;
    int dy = dyq - 1;
    int dx = tap - dyq*3 - 1;
    {
      int yy = yA + dy, xx = xA + dx;
      const uint16_t* pa = ((unsigned)yy < 7u && (unsigned)xx < 7u)
          ? (p1 + (size_t)((nA*49 + yy*7 + xx)*128 + c0 + rq*8))
          : (zp16 + rq*8);
      ra0 = *(const uint4*)pa;
    }
    {
      int yy = yB + dy, xx = xB + dx;
      const uint16_t* pa = ((unsigned)yy < 7u && (unsigned)xx < 7u)
          ? (p1 + (size_t)((nB*49 + yy*7 + xx)*128 + c0 + rq*8))
          : (zp16 + rq*8);
      ra1 = *(const uint4*)pa;
    }
    size_t bb = (size_t)r1*1152 + (size_t)(s*32) + rq*8;
    rb0 = *(const uint4*)(W2s + bb);
    rb1 = *(const uint4*)(W2s + bb + (size_t)64*1152);
    rb2 = *(const uint4*)(W2s + bb + (size_t)128*1152);
    rb3 = *(const uint4*)(W2s + bb + (size_t)192*1152);
  };
  loadstep(0);

  f32x4 zero4 = {0.f,0.f,0.f,0.f};
  f32x4 acc[4][8];
  #pragma unroll
  for (int ia=0;ia<4;ia++)
    #pragma unroll
    for (int jb=0;jb<8;jb++) acc[ia][jb] = zero4;

  for (int s=0; s<36; s++){
    __syncthreads();
    *(uint4*)(smA + r1*40 + rq*8) = ra0;
    *(uint4*)(smA + (r1+64)*40 + rq*8) = ra1;
    *(uint4*)(smB + r1*40 + rq*8) = rb0;
    *(uint4*)(smB + (r1+64)*40 + rq*8) = rb1;
    *(uint4*)(smB + (r1+128)*40 + rq*8) = rb2;
    *(uint4*)(smB + (r1+192)*40 + rq*8) = rb3;
    __syncthreads();
    if (s < 35) loadstep(s+1);       // prefetch overlaps MFMA
    bf16x8 af[4];
    #pragma unroll
    for (int ia=0;ia<4;ia++)
      af[ia] = *(const bf16x8*)(smA + (wm*64 + ia*16 + l15)*40 + quad*8);
    #pragma unroll
    for (int jb=0;jb<8;jb++){
      bf16x8 bb = *(const bf16x8*)(smB + (wn*128 + jb*16 + l15)*40 + quad*8);
      #pragma unroll
      for (int ia=0;ia<4;ia++)
        acc[ia][jb] = mfma16(af[ia], bb, acc[ia][jb]);
    }
  }
  __syncthreads();
  #pragma unroll
  for (int i=0;i<7;i++){
    int ch = tid + i*256;
    if (ch < 1568) ((uint4*)smT)[ch] = ((const uint4*)T2t)[ch];
  }
  float S=0.f, Q=0.f;
  #pragma unroll
  for (int half=0; half<2; half++){
    __syncthreads();
    if (wm == half){
      #pragma unroll
      for (int ia=0;ia<4;ia++){
        #pragma unroll
        for (int reg=0; reg<4; reg++){
          int rl = ia*16 + quad*4 + reg;
          int mm = m0 + half*64 + rl;
          int pos = mm % 49;
          const uint16_t* tr = smT + pos*256 + wn*128;
          uint16_t* zr = smZ + rl*256 + wn*128;
          #pragma unroll
          for (int jb=0;jb<8;jb++){
            int col = jb*16 + l15;
            float z = acc[ia][jb][reg] + b2f(tr[col]);
            zr[col] = f2b(fmaxf(z, 0.0f));
          }
        }
      }
    }
    __syncthreads();
    #pragma unroll
    for (int i2=0;i2<8;i2++){
      int ch = tid + i2*256;
      int row = ch >> 5, off = ch & 31;
      *(uint4*)(zplus + ((size_t)(m0 + half*64 + row))*256 + off*8) = ((const uint4*)smZ)[ch];
    }
    for (int r=0;r<64;r++){
      float v = b2f(smZ[r*256 + tid]);
      S += v; Q += v*v;
    }
  }
  part2[((size_t)blockIdx.x*256 + tid)*2 + 0] = S;
  part2[((size_t)blockIdx.x*256 + tid)*2 + 1] = Q;
}

// --------------------------------------------------------------- k_stats2 ---
__global__ void k_stats2(const float* __restrict__ part2, const float* __restrict__ g2,
                         const float* __restrict__ be2, float* __restrict__ ab2)
{
  __shared__ float sS[256], sQ[256];
  int ch = blockIdx.x, t = threadIdx.x;
  float S=0.f, Q=0.f;
  for (int i=t; i<1568; i+=256){
    S += part2[((size_t)i*256 + ch)*2 + 0];
    Q += part2[((size_t)i*256 + ch)*2 + 1];
  }
  sS[t]=S; sQ[t]=Q;
  __syncthreads();
  for (int s=128; s>0; s>>=1){
    if (t < s){ sS[t]+=sS[t+s]; sQ[t]+=sQ[t+s]; }
    __syncthreads();
  }
  if (t==0){
    float N = 200704.0f;
    float mean = sS[0]/N;
    float var = sQ[0]/N - mean*mean;
    float a = g2[ch] * rsqrtf(var + 1e-5f);
    ab2[ch*2+0] = a;
    ab2[ch*2+1] = be2[ch] - mean*a;
  }
}

// ---------------------------------------------------------------- k_final ---
__global__ __launch_bounds__(256) void k_final(
    const float* __restrict__ paird, const float* __restrict__ fmt,
    const uint16_t* __restrict__ zplus, const float* __restrict__ ab2,
    float* __restrict__ out)
{
  __shared__ float smRes[12544];     // [o][pos] transpose buffer
  __shared__ int   smTI[196];
  __shared__ float smTW[196];
  int n = blockIdx.x, tid = threadIdx.x;
  if (tid < 49){
    const float* pd = paird + (size_t)n*136;
    int py = tid / 7, px = tid - (tid/7)*7;
    float x0 = pd[px],    wx = pd[7+px];
    float y0 = pd[14+py], wy = pd[21+py];
    int x0i = (int)x0, y0i = (int)y0;
    int x1i = min(x0i+1, 36), y1i = min(y0i+1, 36);
    smTI[tid*4+0] = (y0i*37+x0i)*256;
    smTI[tid*4+1] = (y0i*37+x1i)*256;
    smTI[tid*4+2] = (y1i*37+x0i)*256;
    smTI[tid*4+3] = (y1i*37+x1i)*256;
    smTW[tid*4+0] = (1.f-wy)*(1.f-wx);
    smTW[tid*4+1] = (1.f-wy)*wx;
    smTW[tid*4+2] = wy*(1.f-wx);
    smTW[tid*4+3] = wy*wx;
  }
  float a2 = ab2[tid*2+0], c2 = ab2[tid*2+1];   // tid == channel o
  __syncthreads();
  const uint16_t* zrow = zplus + (size_t)n*49*256 + tid;
  int o = tid;
  for (int pos=0; pos<49; pos++){
    float v = smTW[pos*4+0]*fmt[smTI[pos*4+0]+o]
            + smTW[pos*4+1]*fmt[smTI[pos*4+1]+o]
            + smTW[pos*4+2]*fmt[smTI[pos*4+2]+o]
            + smTW[pos*4+3]*fmt[smTI[pos*4+3]+o];
    float z = b2f(zrow[(size_t)pos*256]);
    smRes[o*49 + pos] = v + a2*z + c2;
  }
  __syncthreads();
  float* op = out + (size_t)n*12544;
  for (int i=0;i<49;i++){
    int f = tid + i*256;
    op[f] = smRes[f];
  }
}

// ----------------------------------------------------------- kernel_launch --
extern "C" void kernel_launch(void* const* d_in, const int* in_sizes, int n_in,
                              void* d_out, int out_size, void* d_ws, size_t ws_size,
                              hipStream_t stream)
{
  const float* fmap = (const float*)d_in[0];
  const float* rois = (const float*)d_in[1];
  const int*   ui   = (const int*)d_in[2];
  const float* W1   = (const float*)d_in[3];
  const float* b1   = (const float*)d_in[4];
  const float* g1   = (const float*)d_in[5];
  const float* be1  = (const float*)d_in[6];
  const float* W2   = (const float*)d_in[7];
  const float* b2   = (const float*)d_in[8];
  const float* g2   = (const float*)d_in[9];
  const float* be2  = (const float*)d_in[10];
  float* out = (float*)d_out;
  char* ws = (char*)d_ws;

  constexpr size_t OFF_ZERO = 0;                             // 256 B zero page
  constexpr size_t OFF_PAIR = 256;                           // 4096*136*4
  constexpr size_t OFF_FMT  = OFF_PAIR + 4096u*136*4;        // 350464*4
  constexpr size_t OFF_W1B  = OFF_FMT + 350464u*4;           // 16384*2
  constexpr size_t OFF_P1   = OFF_W1B + 16384u*2;            // 200704*128*2
  constexpr size_t OFF_ZP   = OFF_P1 + (size_t)200704*128*2; // 200704*256*2
  constexpr size_t OFF_W2S  = OFF_ZP + (size_t)200704*256*2; // 294912*2
  constexpr size_t OFF_T2   = OFF_W2S + 294912u*2;           // 12544*2
  constexpr size_t OFF_S1   = OFF_T2 + 12544u*2;             // 4096*128*2*4
  constexpr size_t OFF_AB1  = OFF_S1 + 4096u*128*2*4;        // 128*2*4
  constexpr size_t OFF_S2   = OFF_AB1 + 1024;                // 1568*256*2*4
  constexpr size_t OFF_AB2  = OFF_S2 + 1568u*256*2*4;        // 256*2*4

  float*    zp    = (float*)(ws + OFF_ZERO);
  float*    pair  = (float*)(ws + OFF_PAIR);
  float*    fmt   = (float*)(ws + OFF_FMT);
  uint16_t* W1b   = (uint16_t*)(ws + OFF_W1B);
  uint16_t* p1    = (uint16_t*)(ws + OFF_P1);
  uint16_t* zplus = (uint16_t*)(ws + OFF_ZP);
  uint16_t* W2s   = (uint16_t*)(ws + OFF_W2S);
  uint16_t* T2t   = (uint16_t*)(ws + OFF_T2);
  float*    part1 = (float*)(ws + OFF_S1);
  float*    ab1   = (float*)(ws + OFF_AB1);
  float*    part2 = (float*)(ws + OFF_S2);
  float*    ab2   = (float*)(ws + OFF_AB2);

  k_setup <<<16,   256, 0, stream>>>(rois, ui, pair, zp);
  k_prepw1<<<64,   256, 0, stream>>>(W1, W1b);
  k_fmapt <<<dim3(22,4), 256, 0, stream>>>(fmap, fmt);
  k_conv1 <<<4096, 512, 0, stream>>>(pair, W1b, b1, p1, part1);
  k_stats1<<<128,  256, 0, stream>>>(part1, g1, be1, ab1);
  k_prepb2<<<256,  256, 0, stream>>>(W2, b2, ab1, W2s, T2t);
  k_conv2 <<<1568, 256, 0, stream>>>(p1, W2s, T2t, zp, zplus, part2);
  k_stats2<<<256,  256, 0, stream>>>(part2, g2, be2, ab2);
  k_final <<<4096, 256, 0, stream>>>(pair, fmt, zplus, ab2, out);
}